// Round 1
// baseline (1187.021 us; speedup 1.0000x reference)
//
#include <hip/hip_runtime.h>

typedef unsigned long long u64;
typedef unsigned int u32;

#define MAXN 8704            // 8700 rounded to 64
#define NW   136             // ceil(8700/64)
#define CHUNK 512            // j-chunk for rank kernel

// ---------------- K0: merge + clip + cxcywh->xyxy + sort key ----------------
__global__ void prep_kernel(const float* __restrict__ yb, const float* __restrict__ yc,
                            const float* __restrict__ db, const float* __restrict__ dc,
                            int n1, int n,
                            float4* __restrict__ xyxy, float* __restrict__ conf,
                            u32* __restrict__ key) {
    int i = blockIdx.x * 256 + threadIdx.x;
    if (i >= n) return;
    float cx, cy, w, h, c;
    if (i < n1) {
        const float* b = yb + (size_t)i * 4;
        cx = b[0]; cy = b[1]; w = b[2]; h = b[3]; c = yc[i];
    } else {
        const float* b = db + (size_t)(i - n1) * 4;
        cx = b[0]; cy = b[1]; w = b[2]; h = b[3]; c = dc[i - n1];
    }
    c = fminf(fmaxf(c, 0.0f), 1.0f);          // jnp.clip(conf,0,1)
    float hw = w * 0.5f, hh = h * 0.5f;       // *0.5 is exact, fma-contraction safe
    xyxy[i] = make_float4(cx - hw, cy - hh, cx + hw, cy + hh);
    conf[i] = c;
    key[i]  = __float_as_uint(c);             // conf>=0 -> bit order == value order
}

// ---------------- K1: O(N^2) stable rank (descending conf, ties by index) ---
__global__ void rank_kernel(const u32* __restrict__ key, int n, int* __restrict__ rank) {
    __shared__ __align__(16) u32 sk[CHUNK];
    int t = threadIdx.x;
    int jbase = blockIdx.y * CHUNK;
    for (int s = t; s < CHUNK; s += 256) {
        int j = jbase + s;
        sk[s] = (j < n) ? key[j] : 0u;        // key 0 w/ j>=n contributes nothing
    }
    __syncthreads();
    int i = blockIdx.x * 256 + t;
    if (i >= n) return;
    u32 ki = key[i];
    int cnt = 0;
    const uint4* sk4 = (const uint4*)sk;
    for (int s = 0; s < CHUNK / 4; ++s) {
        uint4 k = sk4[s];                     // broadcast read, conflict-free
        int j = jbase + s * 4;
        cnt += (k.x > ki) || (k.x == ki && (j + 0) < i);
        cnt += (k.y > ki) || (k.y == ki && (j + 1) < i);
        cnt += (k.z > ki) || (k.z == ki && (j + 2) < i);
        cnt += (k.w > ki) || (k.w == ki && (j + 3) < i);
    }
    if (cnt) atomicAdd(&rank[i], cnt);
}

// ---------------- K2: scatter into sorted order -----------------------------
__global__ void scatter_kernel(const float4* __restrict__ xyxy, const float* __restrict__ conf,
                               const int* __restrict__ rank, int n,
                               float4* __restrict__ sbox, float* __restrict__ sconf) {
    int i = blockIdx.x * 256 + threadIdx.x;
    if (i >= n) return;
    int r = rank[i];                          // ranks are a permutation (ties broken)
    sbox[r]  = xyxy[i];
    sconf[r] = conf[i];
}

// ---------------- K3: suppression bit-matrix (upper triangle) ---------------
__global__ void iou_kernel(const float4* __restrict__ sbox, int n, int nw,
                           u64* __restrict__ sup) {
    int bi = blockIdx.y, bj = blockIdx.x;
    if (bj < bi) return;                      // only words w >= row-block are read
    __shared__ float4 cb[64];
    int t  = threadIdx.x;                     // 64 threads = 1 wave
    int j0 = bj * 64;
    int jt = j0 + t;
    cb[t] = (jt < n) ? sbox[jt] : make_float4(0, 0, 0, 0);
    __syncthreads();
    int i = bi * 64 + t;
    if (i >= n) return;
    float4 a = sbox[i];
    float areaA = (a.z - a.x) * (a.w - a.y);
    u64 word = 0;
    int kmax = min(64, n - j0);
    for (int k = 0; k < kmax; ++k) {
        int j = j0 + k;
        float4 b = cb[k];
        float iw = fmaxf(fminf(a.z, b.z) - fmaxf(a.x, b.x), 0.0f);
        float ih = fmaxf(fminf(a.w, b.w) - fmaxf(a.y, b.y), 0.0f);
        float inter = iw * ih;
        float areaB = (b.z - b.x) * (b.w - b.y);
        float uni = areaA + areaB - inter;
        float iou = inter / fmaxf(uni, 1e-9f);   // IEEE div, matches np
        if (j > i && iou > 0.5f) word |= (1ULL << k);
    }
    sup[(size_t)i * nw + bj] = word;
}

// ---------------- K4: serial greedy scan (single block) ---------------------
__global__ void scan_kernel(const u64* __restrict__ sup, int n, int nw,
                            u64* __restrict__ keepw) {
    __shared__ u64 diag[64];
    __shared__ int s_list[64];
    __shared__ int s_cnt;
    int t = threadIdx.x;
    u64 remv = 0;                             // thread t owns remv word t (t < nw)
    for (int b = 0; b < nw; ++b) {
        if (t < 64) {
            int i = b * 64 + t;
            diag[t] = (i < n) ? sup[(size_t)i * nw + b] : 0ULL;
        }
        __syncthreads();
        if (t == b) {                         // sequential 64-bit resolve
            u64 cur = remv;
            u64 kw = 0;
            int cnt = 0;
            int lim = min(64, n - b * 64);
            for (int k = 0; k < lim; ++k) {
                if (!((cur >> k) & 1ULL)) {
                    kw |= (1ULL << k);
                    s_list[cnt++] = k;
                    cur |= diag[k];
                }
            }
            s_cnt = cnt;
            keepw[b] = kw;
        }
        __syncthreads();
        int cnt = s_cnt;
        if (t > b && t < nw) {                // OR kept rows into future words
            u64 r = remv;
            for (int c = 0; c < cnt; ++c) {
                int i = b * 64 + s_list[c];
                r |= sup[(size_t)i * nw + t];
            }
            remv = r;
        }
        __syncthreads();
    }
}

// ---------------- K5: masked output -----------------------------------------
__global__ void out_kernel(const float* __restrict__ sbox, const float* __restrict__ sconf,
                           const u64* __restrict__ keepw, int n, float* __restrict__ out) {
    int e = blockIdx.x * 256 + threadIdx.x;
    if (e >= n * 5) return;
    int r = e / 5, c = e - r * 5;
    float keep = ((keepw[r >> 6] >> (r & 63)) & 1ULL) ? 1.0f : 0.0f;
    float v = (c < 4) ? sbox[r * 4 + c] : sconf[r];
    out[e] = v * keep;
}

extern "C" void kernel_launch(void* const* d_in, const int* in_sizes, int n_in,
                              void* d_out, int out_size, void* d_ws, size_t ws_size,
                              hipStream_t stream) {
    const float* yb = (const float*)d_in[0];   // yolo_cxcywh   (8400,4)
    const float* yc = (const float*)d_in[1];   // yolo_person_conf (8400,)
    const float* db = (const float*)d_in[2];   // rtdetr_cxcywh (300,4)
    const float* dc = (const float*)d_in[3];   // rtdetr_person_conf (300,)
    int n1 = in_sizes[1];
    int n2 = in_sizes[3];
    int n  = n1 + n2;                          // 8700
    int nw = (n + 63) / 64;                    // 136

    // workspace layout (all 16B-aligned), ~9.9 MB total
    char* w = (char*)d_ws;
    u64*    sup   = (u64*)w;                                   // MAXN*NW*8 = 9,469,952
    float4* xyxy  = (float4*)(w + (size_t)MAXN * NW * 8);      // 139,264
    float4* sbox  = xyxy + MAXN;                               // 139,264
    float*  conf  = (float*)(sbox + MAXN);                     // 34,816
    float*  sconf = conf + MAXN;                               // 34,816
    u32*    key   = (u32*)(sconf + MAXN);                      // 34,816
    int*    rank  = (int*)(key + MAXN);                        // 34,816
    u64*    keepw = (u64*)(rank + MAXN);                       // 1,088

    hipMemsetAsync(rank, 0, MAXN * sizeof(int), stream);       // ws is poisoned 0xAA

    int nb = (n + 255) / 256;                                  // 34
    prep_kernel<<<nb, 256, 0, stream>>>(yb, yc, db, dc, n1, n, xyxy, conf, key);

    dim3 g1(nb, (n + CHUNK - 1) / CHUNK);                      // 34 x 17
    rank_kernel<<<g1, 256, 0, stream>>>(key, n, rank);

    scatter_kernel<<<nb, 256, 0, stream>>>(xyxy, conf, rank, n, sbox, sconf);

    dim3 g3(nw, nw);                                           // 136 x 136, 64 thr
    iou_kernel<<<g3, 64, 0, stream>>>(sbox, n, nw, sup);

    scan_kernel<<<1, 256, 0, stream>>>(sup, n, nw, keepw);

    out_kernel<<<(n * 5 + 255) / 256, 256, 0, stream>>>((const float*)sbox, sconf,
                                                        keepw, n, (float*)d_out);
}